// Round 11
// baseline (261.135 us; speedup 1.0000x reference)
//
#include <hip/hip_runtime.h>
#include <math.h>

// B=4096, IN=1024, H=2048, OUT=1024
// cosmic layer == broadcast prob[r] = (1/H)*(prod_{d,k} cos(cw[d,r,k]))^2
// Network = 6 fp16-MFMA GEMMs (16x16x32) with fused bias/relu/tanh epilogues.
//
// r11: k-major tiled operand layout everywhere:
//   off(r,k) = (k>>5)*(R*32) + ((k>>3)&3)*(R*8) + r*8 + (k&7)
// -> frag reads are lane-consecutive granules (conflict-free, no XOR),
//    staging is a linear coalesced copy, BK=32 legal.
// GEMM: 256x128 tile, 256 thr (4 waves 2Mx2N of 128x64; reads/MFMA=0.375),
// dbuf 48 KB -> 2 blocks/CU (independent barrier domains, m114 overlap),
// counted vmcnt (T4), split lgkm (rule 18 fences), setprio (T5), XCD (T1).

typedef _Float16 f16;
typedef _Float16 f16x8 __attribute__((ext_vector_type(8)));
typedef float f32x4 __attribute__((ext_vector_type(4)));

#define GLD16(gp, lp) __builtin_amdgcn_global_load_lds( \
    (const __attribute__((address_space(1))) unsigned int*)(gp), \
    (__attribute__((address_space(3))) unsigned int*)(lp), 16, 0, 0)

__device__ __forceinline__ float tanh_fast(float x) {
  return 1.0f - 2.0f / (__expf(2.0f * x) + 1.0f);
}

// ---- cast x (4096xK f32 row-major) -> k-major tiled f16 (R=4096) ----
// output-granule-linear: g -> kt=g>>14, cc=(g>>12)&3, r=g&4095
__global__ void cast_tiled(const float* __restrict__ x, f16* __restrict__ out,
                           int n_gran, int K) {
  int g = blockIdx.x * 256 + threadIdx.x;
  if (g >= n_gran) return;
  int r  = g & 4095;
  int cc = (g >> 12) & 3;
  int kt = g >> 14;
  const float* s = x + (size_t)r * K + kt * 32 + cc * 8;
  float4 v0 = *(const float4*)s;
  float4 v1 = *(const float4*)(s + 4);
  f16x8 o = { (f16)v0.x, (f16)v0.y, (f16)v0.z, (f16)v0.w,
              (f16)v1.x, (f16)v1.y, (f16)v1.z, (f16)v1.w };
  *(f16x8*)&out[(size_t)g * 8] = o;
}

// ------- merged cast+transpose: W (K,N) f32 -> k-major tiled WT' (R=N) -------
struct TD { const float* src; f16* dst; int K; int N; };
struct TD6 { TD d[6]; };

__global__ void cast_transpose6(TD6 a) {
  TD d = a.d[blockIdx.z];
  const int bx = blockIdx.x * 64;   // N
  const int by = blockIdx.y * 32;   // K
  if (bx >= d.N || by >= d.K) return;
  __shared__ float tile[32][68];
  const int t = threadIdx.x;
#pragma unroll
  for (int pass = 0; pass < 2; ++pass) {
    int idx = t + pass * 256;
    int row = idx >> 4;
    int c4  = (idx & 15) * 4;
    float4 v = *(const float4*)&d.src[(size_t)(by + row) * d.N + bx + c4];
    *(float4*)&tile[row][c4] = v;
  }
  __syncthreads();
  const int nl = t >> 2;            // n within 64-tile
  const int k8 = (t & 3) * 8;       // k within 32-tile
  f16x8 o;
#pragma unroll
  for (int j = 0; j < 8; ++j) o[j] = (f16)tile[k8 + j][nl];
  size_t off = (size_t)(by >> 5) * ((size_t)d.N * 32) +
               (size_t)(k8 >> 3) * ((size_t)d.N * 8) + (size_t)(bx + nl) * 8;
  *(f16x8*)&d.dst[off] = o;
}

// ---------------- cosmic prob, 2-pass, both tensors fused ----------------
__global__ void cosmic_pp2(const float* __restrict__ cw1, const float* __restrict__ cw2,
                           float* __restrict__ pp, int H) {
  int i = blockIdx.x * 256 + threadIdx.x;   // 0 .. 16H
  if (i >= 16 * H) return;
  const float* cw = (i < 8 * H) ? cw1 : cw2;
  int j = (i < 8 * H) ? i : i - 8 * H;
  const float* a = cw + (size_t)j * H;
  pp[i] = cosf(a[0]) * cosf(a[1]) * cosf(a[2]);
}
__global__ void cosmic_fin2(const float* __restrict__ pp, float* __restrict__ p1,
                            float* __restrict__ p2, int H) {
  int r = blockIdx.x * 256 + threadIdx.x;   // 0 .. 2H
  if (r >= 2 * H) return;
  int rr = (r < H) ? r : r - H;
  const float* base = pp + ((r < H) ? 0 : 8 * H);
  float p = 1.0f;
#pragma unroll
  for (int d = 0; d < 8; ++d) p *= base[d * H + rr];
  float v = p * p / (float)H;
  if (r < H) p1[rr] = v; else p2[rr] = v;
}

// ---------------- fp16 MFMA GEMM (16x16x32), BK=32, k-major tiled ----------------
// A: tiled (R=M). Bt: tiled (R=N). Output EPI 0/1: tiled f16 (R=M); EPI 2: row-major f32.
// 256 thr = 4 waves WM x WN; per-wave (BM/WM) x (BN/WN).
template <int EPI, int BM, int BN, int WM, int WN>
__global__ __launch_bounds__(256, 2)
void gemm_f16(const f16* __restrict__ A, const f16* __restrict__ Bt,
              const float* __restrict__ bias, const float* __restrict__ prob,
              f16* __restrict__ Ch, float* __restrict__ Cf,
              int M, int N, int K, int GX) {
  constexpr int MR   = BM / (WM * 16);     // 8 (main) / 4 (G5)
  constexpr int NR   = BN / (WN * 16);     // 4 / 2
  constexpr int ABUF = BM * 32;            // f16 per A buffer
  constexpr int BBUF = BN * 32;
  constexpr int RA   = BM / 64;            // stage rounds (256 thr * 8 f16)
  constexpr int RB   = BN / 64;
  constexpr int NLD  = RA + RB;
  constexpr int LBM  = (BM == 256) ? 8 : 7;
  constexpr int LBN  = (BN == 128) ? 7 : 6;
  __shared__ f16 lds[2 * (ABUF + BBUF)];   // 48 KB main / 24 KB G5
  f16* As = lds;
  f16* Bs = lds + 2 * ABUF;

  const int t = threadIdx.x;
  const int nwg = gridDim.x, bid = blockIdx.x;
  const int swz = (bid & 7) * (nwg >> 3) + (bid >> 3);   // XCD swizzle (nwg%8==0)
  const int bx = swz % GX, by = swz / GX;
  const int m0 = by * BM, n0 = bx * BN;

  // staging: pure linear copy (both sides tiled). Each wave's 64 lanes are
  // consecutive granules within one cc-stripe -> coalesced global, linear LDS.
  auto stage_all = [&](int kt, int buf) {
    const size_t abase = (size_t)kt * M * 32;
#pragma unroll
    for (int q = 0; q < RA; ++q) {
      int g = q * 256 + t;
      int cc = g >> LBM, r = g & (BM - 1);
      GLD16(A + abase + (size_t)cc * M * 8 + (size_t)(m0 + r) * 8,
            As + buf * ABUF + g * 8);
    }
    const size_t bbase = (size_t)kt * N * 32;
#pragma unroll
    for (int q = 0; q < RB; ++q) {
      int g = q * 256 + t;
      int cc = g >> LBN, r = g & (BN - 1);
      GLD16(Bt + bbase + (size_t)cc * N * 8 + (size_t)(n0 + r) * 8,
            Bs + buf * BBUF + g * 8);
    }
  };

  const int wave = t >> 6, lane = t & 63;
  const int wr = wave / WN, wc = wave % WN;
  const int l16 = lane & 15, kq = lane >> 4;   // kq = cc chunk of K-32

  f32x4 acc[MR][NR] = {};
  const int nt = K >> 5;

  stage_all(0, 0);
  stage_all(1, 1);
  int cur = 0;
  for (int kt = 0; kt < nt; ++kt) {
    if (kt + 1 < nt) asm volatile("s_waitcnt vmcnt(%0)" :: "i"(NLD) : "memory");
    else             asm volatile("s_waitcnt vmcnt(0)" ::: "memory");
    __builtin_amdgcn_s_barrier();

    const f16* Ab = As + cur * ABUF;
    const f16* Bb = Bs + cur * BBUF;
    f16x8 b[NR], a[MR];
#pragma unroll
    for (int nr = 0; nr < NR; ++nr) {
      int row = wc * (NR * 16) + nr * 16 + l16;
      b[nr] = *(const f16x8*)&Bb[kq * (BN * 8) + row * 8];
    }
#pragma unroll
    for (int mr = 0; mr < MR; ++mr) {
      int row = wr * (MR * 16) + mr * 16 + l16;
      a[mr] = *(const f16x8*)&Ab[kq * (BM * 8) + row * 8];
    }
    // first half: b[*] + a[0..MR/2) ready; a-second-half hides under MFMA
    asm volatile("s_waitcnt lgkmcnt(%0)" :: "i"(MR / 2) : "memory");
    __builtin_amdgcn_sched_barrier(0);
    __builtin_amdgcn_s_setprio(1);
#pragma unroll
    for (int mr = 0; mr < MR / 2; ++mr)
#pragma unroll
      for (int nr = 0; nr < NR; ++nr)
        acc[mr][nr] = __builtin_amdgcn_mfma_f32_16x16x32_f16(a[mr], b[nr], acc[mr][nr], 0, 0, 0);
    __builtin_amdgcn_s_setprio(0);
    asm volatile("s_waitcnt lgkmcnt(0)" ::: "memory");
    __builtin_amdgcn_sched_barrier(0);
    __builtin_amdgcn_s_barrier();               // all waves done reading buf cur
    if (kt + 2 < nt) stage_all(kt + 2, cur);    // refill just-freed buffer
    __builtin_amdgcn_sched_barrier(0);
    __builtin_amdgcn_s_setprio(1);
#pragma unroll
    for (int mr = MR / 2; mr < MR; ++mr)
#pragma unroll
      for (int nr = 0; nr < NR; ++nr)
        acc[mr][nr] = __builtin_amdgcn_mfma_f32_16x16x32_f16(a[mr], b[nr], acc[mr][nr], 0, 0, 0);
    __builtin_amdgcn_s_setprio(0);
    cur ^= 1;
  }

  // epilogue: C/D layout col=lane&15, row=(lane>>4)*4+q.
  // EPI 0/1 write k-major tiled (R=M, k=col); EPI 2 writes row-major f32.
#pragma unroll
  for (int nr = 0; nr < NR; ++nr) {
    const int col = n0 + wc * (NR * 16) + nr * 16 + l16;
    float bn = bias[col];
    if (EPI == 1) bn += prob[col];
    const size_t cb = (size_t)(col >> 5) * ((size_t)M * 32) +
                      (size_t)((col >> 3) & 3) * ((size_t)M * 8) + (col & 7);
#pragma unroll
    for (int mr = 0; mr < MR; ++mr) {
      const int rbase = m0 + wr * (MR * 16) + mr * 16 + kq * 4;
#pragma unroll
      for (int q = 0; q < 4; ++q) {
        float v = acc[mr][nr][q] + bn;
        if (EPI == 1) v = tanh_fast(v);
        else v = fmaxf(v, 0.0f);
        if (EPI == 2) Cf[(size_t)(rbase + q) * N + col] = v;
        else Ch[cb + (size_t)(rbase + q) * 8] = (f16)v;
      }
    }
  }
}

extern "C" void kernel_launch(void* const* d_in, const int* in_sizes, int n_in,
                              void* d_out, int out_size, void* d_ws, size_t ws_size,
                              hipStream_t stream) {
  const float* x   = (const float*)d_in[0];
  const float* W0  = (const float*)d_in[1];
  const float* b0  = (const float*)d_in[2];
  const float* W1  = (const float*)d_in[3];
  const float* b1  = (const float*)d_in[4];
  const float* cw1 = (const float*)d_in[5];
  const float* KW1 = (const float*)d_in[7];
  const float* Kb1 = (const float*)d_in[8];
  const float* W2  = (const float*)d_in[9];
  const float* b2  = (const float*)d_in[10];
  const float* cw2 = (const float*)d_in[11];
  const float* KW2 = (const float*)d_in[13];
  const float* Kb2 = (const float*)d_in[14];
  const float* W3  = (const float*)d_in[15];
  const float* b3  = (const float*)d_in[16];

  const int B = 4096, IN = 1024, H = 2048, OUT = 1024;

  char* ws = (char*)d_ws;
  size_t off = 0;
  auto alloc = [&](size_t bytes) {
    char* p = ws + off;
    off = (off + bytes + 255) & ~(size_t)255;
    return p;
  };
  f16* xh    = (f16*)alloc((size_t)B * IN * 2);
  f16* W0T   = (f16*)alloc((size_t)H * IN * 2);
  f16* W1T   = (f16*)alloc((size_t)H * H * 2);
  f16* KW1T  = (f16*)alloc((size_t)H * H * 2);
  f16* W2T   = (f16*)alloc((size_t)H * H * 2);
  f16* KW2T  = (f16*)alloc((size_t)H * H * 2);
  f16* W3T   = (f16*)alloc((size_t)OUT * H * 2);
  f16* hA    = (f16*)alloc((size_t)B * H * 2);
  f16* hB    = (f16*)alloc((size_t)B * H * 2);
  float* p1  = (float*)alloc((size_t)H * 4);
  float* p2  = (float*)alloc((size_t)H * 4);
  float* pp  = (float*)alloc((size_t)16 * H * 4);
  (void)ws_size;

  // x -> tiled f16
  {
    int n_gran = B * IN / 8;
    cast_tiled<<<(n_gran + 255) / 256, 256, 0, stream>>>(x, xh, n_gran, IN);
  }

  TD6 td;
  td.d[0] = { W0,  W0T,  IN, H };
  td.d[1] = { W1,  W1T,  H,  H };
  td.d[2] = { KW1, KW1T, H,  H };
  td.d[3] = { W2,  W2T,  H,  H };
  td.d[4] = { KW2, KW2T, H,  H };
  td.d[5] = { W3,  W3T,  H,  OUT };
  cast_transpose6<<<dim3(H / 64, H / 32, 6), 256, 0, stream>>>(td);

  cosmic_pp2<<<(16 * H + 255) / 256, 256, 0, stream>>>(cw1, cw2, pp, H);
  cosmic_fin2<<<(2 * H + 255) / 256, 256, 0, stream>>>(pp, p1, p2, H);

  // G0-G4: 256x128 tile, 4 waves 2x2 of 128x64, grid 16x16=256, 2 blk/CU.
  {
    int gx = H / 128;
    dim3 g(gx * (B / 256));
    gemm_f16<0, 256, 128, 2, 2><<<g, 256, 0, stream>>>(xh, W0T, b0,  nullptr, hA, nullptr, B, H, IN, gx);
    gemm_f16<0, 256, 128, 2, 2><<<g, 256, 0, stream>>>(hA, W1T, b1,  nullptr, hB, nullptr, B, H, H,  gx);
    gemm_f16<1, 256, 128, 2, 2><<<g, 256, 0, stream>>>(hB, KW1T, Kb1, p1,     hA, nullptr, B, H, H,  gx);
    gemm_f16<0, 256, 128, 2, 2><<<g, 256, 0, stream>>>(hA, W2T, b2,  nullptr, hB, nullptr, B, H, H,  gx);
    gemm_f16<1, 256, 128, 2, 2><<<g, 256, 0, stream>>>(hB, KW2T, Kb2, p2,     hA, nullptr, B, H, H,  gx);
  }
  // G5: 128x64 tile, 4 waves 2x2 of 64x32... (MR=4,NR=2), grid 16x32=512, 2 blk/CU.
  {
    int gx = OUT / 64;
    dim3 g(gx * (B / 128));
    gemm_f16<2, 128, 64, 2, 2><<<g, 256, 0, stream>>>(hA, W3T, b3, nullptr, nullptr, (float*)d_out, B, OUT, H, gx);
  }
}